// Round 8
// baseline (902.265 us; speedup 1.0000x reference)
//
#include <hip/hip_runtime.h>
#include <hip/hip_bf16.h>

typedef unsigned short u16;
typedef __attribute__((ext_vector_type(8))) short bf16x8;
typedef __attribute__((ext_vector_type(4))) float f32x4;

#define AS1 __attribute__((address_space(1)))
#define AS3 __attribute__((address_space(3)))

// ---- constants for this problem ----
#define Bx 8
#define Tt 2048
#define Dd 1024
#define Nn 256
#define Mm (Bx*Tt)          // 16384
#define CHAINS (Bx*Nn)      // 2048
#define NCH 32
#define TC 64               // T / NCH
#define NCOMB 1792          // 768 (abc) + 1024 (d)

#define WS_NEED 130809856u

__device__ __forceinline__ u16 f2bf(float f) {
  union { float f; unsigned u; } v; v.f = f;
  unsigned u = v.u;
  u += 0x7fffu + ((u >> 16) & 1u);   // RNE
  return (u16)(u >> 16);
}

__device__ __forceinline__ float bf2f(u16 h) {
  union { unsigned u; float f; } v; v.u = ((unsigned)h) << 16;
  return v.f;
}

__device__ __forceinline__ void gload_lds16(const void* g, void* l) {
  __builtin_amdgcn_global_load_lds((AS1 void*)(g), (AS3 void*)(l), 16, 0, 0);
}

// ---------------- x fp32 -> bf16 ----------------
__global__ void cvt_x_kernel(const float* __restrict__ x, u16* __restrict__ xb) {
  int i = blockIdx.x * blockDim.x + threadIdx.x;      // 4 floats per thread
  float4 v = ((const float4*)x)[i];
  unsigned lo = (unsigned)f2bf(v.x) | ((unsigned)f2bf(v.y) << 16);
  unsigned hi = (unsigned)f2bf(v.z) | ((unsigned)f2bf(v.w) << 16);
  ((uint2*)xb)[i] = make_uint2(lo, hi);
}

// ---------------- weight pack: transpose + convert ----------------
__global__ void pack_w_kernel(const float* __restrict__ Wa, const float* __restrict__ Wb,
                              const float* __restrict__ Wc, const float* __restrict__ Wd,
                              const float* __restrict__ Wy,
                              u16* __restrict__ Wcomb, u16* __restrict__ Wyt) {
  __shared__ float tile[32][33];
  int z = blockIdx.z;
  const float* src; u16* dst; int R, C, dld;
  if (z < 3)       { src = (z==0?Wa:(z==1?Wb:Wc)); dst = Wcomb + (size_t)z*256*1024; R=1024; C=256;  dld=1024; }
  else if (z == 3) { src = Wd; dst = Wcomb + (size_t)768*1024; R=1024; C=1024; dld=1024; }
  else             { src = Wy; dst = Wyt; R=256;  C=1024; dld=256;  }
  int c0 = blockIdx.x * 32, r0 = blockIdx.y * 32;
  if (c0 >= C || r0 >= R) return;
  int tx = threadIdx.x & 31, ty = threadIdx.x >> 5;   // 32x8
  #pragma unroll
  for (int i = 0; i < 32; i += 8)
    tile[ty + i][tx] = src[(size_t)(r0 + ty + i)*C + (c0 + tx)];
  __syncthreads();
  #pragma unroll
  for (int i = 0; i < 32; i += 8) {
    int c = c0 + ty + i, r = r0 + tx;
    dst[(size_t)c*dld + r] = f2bf(tile[tx][ty + i]);
  }
}

// ---------------- 128x256 GEMM (BM=128, BN=256, BK=64) ----------------
// Round-2-proven syncthreads structure, widened N-tile for 2x arithmetic
// intensity on A. 4 waves (2 wm x 2 wn); wave output 64x128 (acc[4][8]).
// LDS 48 KiB single-buffer -> 2 blocks/CU co-resident hide staging latency.
// Slot-XOR swizzle (T2, both-sides): linear LDS dest for global_load_lds,
// pre-swizzled global source slot, same XOR on ds_read (G21).
// XCD swizzle: nt fastest within each XCD's contiguous chunk -> Wcomb (3.7MB)
// stays L2-resident per XCD; A-panel reused across gx consecutive blocks.
// EPI 0: nt 0/1/2 -> abc (ld 768) with sigmoid/+bias/tanh; nt>=3 -> d
//        (bf16 dtmp if available, else f32 outO).
// EPI 2: outO = acc + b0[col] + dtmp[row,col]  (or += if no dtmp)
template<int EPI>
__global__ __launch_bounds__(256, 2) void gemm_bn256_kernel(
    const u16* __restrict__ A, const u16* __restrict__ Bt, int K, int gx,
    float* __restrict__ outA, float* __restrict__ outO, u16* __restrict__ dtmp,
    const float* __restrict__ b0, const float* __restrict__ b1,
    const float* __restrict__ b2, const float* __restrict__ b3) {
  __shared__ u16 ldsA[128*64];
  __shared__ u16 ldsB[256*64];
  const int tid = threadIdx.x;
  const int lane = tid & 63, wid = tid >> 6;
  const int wm = wid >> 1, wn = wid & 1;

  // XCD-aware swizzle (gridDim.x % 8 == 0, (gridDim.x/8) % gx == 0)
  const int h = blockIdx.x, xcd = h & 7, j = h >> 3;
  const int nt = j % gx;
  const int mt = xcd * ((gridDim.x >> 3) / gx) + j / gx;
  const int m0 = mt * 128, n0 = nt * 256;
  const int NT = K >> 6;

  // staging mapping: thread covers (row rl of 32-row unit, 16B slot ssl)
  const int rl  = tid >> 3;                  // 0..31
  const int ssl = (tid & 7) ^ (rl & 7);      // pre-swizzled source slot

  // fragment-read lane mapping
  const int lr = lane & 15, kq = lane >> 4, sw = lane & 7;

  f32x4 acc[4][8] = {};

  for (int t = 0; t < NT; ++t) {
    const int k0 = t << 6;
    #pragma unroll
    for (int u = 0; u < 4; ++u)              // A: 128 rows = 4 units
      gload_lds16(A + (size_t)(m0 + u*32 + rl)*K + k0 + ssl*8,
                  ldsA + u*2048 + wid*512);
    #pragma unroll
    for (int u = 0; u < 8; ++u)              // B: 256 rows = 8 units
      gload_lds16(Bt + (size_t)(n0 + u*32 + rl)*K + k0 + ssl*8,
                  ldsB + u*2048 + wid*512);
    __syncthreads();                         // drains vmcnt: tile ready

    bf16x8 af[4][2];
    #pragma unroll
    for (int mi = 0; mi < 4; ++mi)
      #pragma unroll
      for (int kk = 0; kk < 2; ++kk)
        af[mi][kk] = *(const bf16x8*)&ldsA[(wm*64 + mi*16 + lr)*64 + (((kk*4 + kq) ^ sw) << 3)];
    #pragma unroll
    for (int ni = 0; ni < 8; ++ni) {
      const int brow = (wn*128 + ni*16 + lr)*64;
      bf16x8 bf0 = *(const bf16x8*)&ldsB[brow + (((0 + kq) ^ sw) << 3)];
      bf16x8 bf1 = *(const bf16x8*)&ldsB[brow + (((4 + kq) ^ sw) << 3)];
      #pragma unroll
      for (int mi = 0; mi < 4; ++mi) {
        acc[mi][ni] = __builtin_amdgcn_mfma_f32_16x16x32_bf16(af[mi][0], bf0, acc[mi][ni], 0, 0, 0);
        acc[mi][ni] = __builtin_amdgcn_mfma_f32_16x16x32_bf16(af[mi][1], bf1, acc[mi][ni], 0, 0, 0);
      }
    }
    __syncthreads();                         // protect buffer overwrite
  }

  // ---- epilogue: C/D layout col=lane&15, row=(lane>>4)*4+r [m89-verified] ----
  const int orow = (lane >> 4) * 4;
  const int ocol = lane & 15;
  #pragma unroll
  for (int mi = 0; mi < 4; ++mi)
  #pragma unroll
  for (int ni = 0; ni < 8; ++ni) {
    const int rowb = m0 + wm*64 + mi*16 + orow;
    const int coln = n0 + wn*128 + ni*16 + ocol;
    #pragma unroll
    for (int r = 0; r < 4; ++r) {
      const int row = rowb + r;
      float v = acc[mi][ni][r];
      if (EPI == 0) {
        if (coln < 256) {
          v = 1.f / (1.f + __expf(-(v + b0[coln])));
          outA[(size_t)row*768 + coln] = v;
        } else if (coln < 512) {
          outA[(size_t)row*768 + coln] = v + b1[coln - 256];
        } else if (coln < 768) {
          outA[(size_t)row*768 + coln] = tanhf(v + b2[coln - 512]);
        } else {
          const int col = coln - 768;
          if (dtmp) dtmp[(size_t)row*1024 + col] = f2bf(v + b3[col]);
          else      outO[(size_t)row*1024 + col] = v + b3[col];
        }
      } else {
        const size_t o = (size_t)row*1024 + coln;
        if (dtmp) outO[o] = v + b0[coln] + bf2f(dtmp[o]);
        else      outO[o] = outO[o] + v + b0[coln];
      }
    }
  }
}

// ---------------- scan: s_t = a*s + (1-a)*b ; cs = c*s ----------------
__global__ void scanA_kernel(const float* __restrict__ abc,
                             float* __restrict__ Asum, float* __restrict__ Usum) {
  int idx = blockIdx.x * blockDim.x + threadIdx.x;    // chunk*2048 + chain
  int chain = idx & (CHAINS - 1);
  int ch = idx >> 11;
  int bb = chain >> 8, n = chain & 255;
  const float* base = abc + (size_t)(bb*Tt + ch*TC) * 768;
  float A = 1.f, U = 0.f;
  for (int t = 0; t < TC; ++t) {
    float a = base[(size_t)t*768 + n];
    float b = base[(size_t)t*768 + 256 + n];
    U = a*U + (1.f - a)*b;
    A *= a;
  }
  Asum[idx] = A; Usum[idx] = U;
}

__global__ void scanB_kernel(const float* __restrict__ Asum, const float* __restrict__ Usum,
                             float* __restrict__ Spre) {
  int chain = blockIdx.x * blockDim.x + threadIdx.x;  // 0..2047
  float s = 0.f;
  for (int ch = 0; ch < NCH; ++ch) {
    int i = (ch << 11) + chain;
    Spre[i] = s;
    s = Asum[i]*s + Usum[i];
  }
}

__global__ void scanC_kernel(const float* __restrict__ abc, const float* __restrict__ Spre,
                             u16* __restrict__ cs) {
  int idx = blockIdx.x * blockDim.x + threadIdx.x;
  int chain = idx & (CHAINS - 1);
  int ch = idx >> 11;
  int bb = chain >> 8, n = chain & 255;
  const float* base = abc + (size_t)(bb*Tt + ch*TC) * 768;
  u16* csb = cs + (size_t)(bb*Tt + ch*TC) * 256 + n;
  float s = Spre[idx];
  for (int t = 0; t < TC; ++t) {
    float a = base[(size_t)t*768 + n];
    float b = base[(size_t)t*768 + 256 + n];
    float c = base[(size_t)t*768 + 512 + n];
    s = a*s + (1.f - a)*b;
    csb[(size_t)t*256] = f2bf(c*s);
  }
}

extern "C" void kernel_launch(void* const* d_in, const int* in_sizes, int n_in,
                              void* d_out, int out_size, void* d_ws, size_t ws_size,
                              hipStream_t stream) {
  const float* x  = (const float*)d_in[0];
  const float* Wa = (const float*)d_in[1];
  const float* ba = (const float*)d_in[2];
  const float* Wb = (const float*)d_in[3];
  const float* bb = (const float*)d_in[4];
  const float* Wc = (const float*)d_in[5];
  const float* bc = (const float*)d_in[6];
  const float* Wd = (const float*)d_in[7];
  const float* bd = (const float*)d_in[8];
  const float* Wy = (const float*)d_in[9];
  const float* by = (const float*)d_in[10];
  float* out = (float*)d_out;
  char* ws = (char*)d_ws;

  // workspace layout (bytes)
  u16*  xb    = (u16*) (ws + 0);          // 33,554,432
  u16*  Wcomb = (u16*) (ws + 33554432);   //  3,670,016
  u16*  Wyt   = (u16*) (ws + 37224448);   //    524,288
  float* abc  = (float*)(ws + 37748736);  // 50,331,648
  u16*  cs    = (u16*) (ws + 88080384);   //  8,388,608
  float* Asum = (float*)(ws + 96468992);  //    262,144
  float* Usum = (float*)(ws + 96731136);  //    262,144
  float* Spre = (float*)(ws + 96993280);  //    262,144
  u16*  dtmp  = (ws_size >= WS_NEED) ? (u16*)(ws + 97255424) : nullptr; // 33,554,432

  // 1) convert x to bf16
  cvt_x_kernel<<<Mm*Dd/4/256, 256, 0, stream>>>(x, xb);
  // 2) pack weights (transposed bf16, [Wa|Wb|Wc|Wd] fused)
  pack_w_kernel<<<dim3(32, 32, 5), 256, 0, stream>>>(Wa, Wb, Wc, Wd, Wy, Wcomb, Wyt);
  // 3) fused GEMM: abc = act(x@[Wa|Wb|Wc]+bias), dtmp = x@Wd + bd (bf16)
  //    grid = (16384/128) * (1792/256) = 128*7 = 896 (div by 8; 112/7=16 ok)
  gemm_bn256_kernel<0><<<896, 256, 0, stream>>>(
      xb, Wcomb, Dd, NCOMB/256, abc, out, dtmp, ba, bb, bc, bd);
  // 4) chunked scan
  scanA_kernel<<<CHAINS*NCH/256, 256, 0, stream>>>(abc, Asum, Usum);
  scanB_kernel<<<CHAINS/256, 256, 0, stream>>>(Asum, Usum, Spre);
  scanC_kernel<<<CHAINS*NCH/256, 256, 0, stream>>>(abc, Spre, cs);
  // 5) out = cs @ Wy + by + dtmp   grid = 128*4 = 512 (div by 8; 64/4=16 ok)
  gemm_bn256_kernel<2><<<512, 256, 0, stream>>>(
      cs, Wyt, Nn, Dd/256, nullptr, out, dtmp, by, nullptr, nullptr, nullptr);
}

// Round 9
// 174.534 us; speedup vs baseline: 5.1696x; 5.1696x over previous
//
#include <hip/hip_runtime.h>
#include <hip/hip_bf16.h>

typedef unsigned short u16;
typedef __attribute__((ext_vector_type(8))) short bf16x8;
typedef __attribute__((ext_vector_type(4))) float f32x4;

#define AS1 __attribute__((address_space(1)))
#define AS3 __attribute__((address_space(3)))

// ---- constants for this problem ----
#define Bx 8
#define Tt 2048
#define Dd 1024
#define Nn 256
#define Mm (Bx*Tt)          // 16384
#define CHAINS (Bx*Nn)      // 2048
#define NCH 32
#define TC 64               // T / NCH
#define NCOMB 1792          // 768 (abc) + 1024 (d)

#define WS_NEED 130809856u

__device__ __forceinline__ u16 f2bf(float f) {
  union { float f; unsigned u; } v; v.f = f;
  unsigned u = v.u;
  u += 0x7fffu + ((u >> 16) & 1u);   // RNE
  return (u16)(u >> 16);
}

__device__ __forceinline__ float bf2f(u16 h) {
  union { unsigned u; float f; } v; v.u = ((unsigned)h) << 16;
  return v.f;
}

__device__ __forceinline__ void gload_lds16(const void* g, void* l) {
  __builtin_amdgcn_global_load_lds((AS1 void*)(g), (AS3 void*)(l), 16, 0, 0);
}

// ---------------- x fp32 -> bf16 ----------------
__global__ void cvt_x_kernel(const float* __restrict__ x, u16* __restrict__ xb) {
  int i = blockIdx.x * blockDim.x + threadIdx.x;      // 4 floats per thread
  float4 v = ((const float4*)x)[i];
  unsigned lo = (unsigned)f2bf(v.x) | ((unsigned)f2bf(v.y) << 16);
  unsigned hi = (unsigned)f2bf(v.z) | ((unsigned)f2bf(v.w) << 16);
  ((uint2*)xb)[i] = make_uint2(lo, hi);
}

// ---------------- weight pack: transpose + convert ----------------
__global__ void pack_w_kernel(const float* __restrict__ Wa, const float* __restrict__ Wb,
                              const float* __restrict__ Wc, const float* __restrict__ Wd,
                              const float* __restrict__ Wy,
                              u16* __restrict__ Wcomb, u16* __restrict__ Wyt) {
  __shared__ float tile[32][33];
  int z = blockIdx.z;
  const float* src; u16* dst; int R, C, dld;
  if (z < 3)       { src = (z==0?Wa:(z==1?Wb:Wc)); dst = Wcomb + (size_t)z*256*1024; R=1024; C=256;  dld=1024; }
  else if (z == 3) { src = Wd; dst = Wcomb + (size_t)768*1024; R=1024; C=1024; dld=1024; }
  else             { src = Wy; dst = Wyt; R=256;  C=1024; dld=256;  }
  int c0 = blockIdx.x * 32, r0 = blockIdx.y * 32;
  if (c0 >= C || r0 >= R) return;
  int tx = threadIdx.x & 31, ty = threadIdx.x >> 5;   // 32x8
  #pragma unroll
  for (int i = 0; i < 32; i += 8)
    tile[ty + i][tx] = src[(size_t)(r0 + ty + i)*C + (c0 + tx)];
  __syncthreads();
  #pragma unroll
  for (int i = 0; i < 32; i += 8) {
    int c = c0 + ty + i, r = r0 + tx;
    dst[(size_t)c*dld + r] = f2bf(tile[tx][ty + i]);
  }
}

// ---------------- GEMM: C[M,*] = A[M,K] * Bt[*,K]^T, bf16 in, fp32 acc ----
// ROUND-2 PROVEN STRUCTURE (146us EPI0): BM=BN=128, BK=64, 4 waves, 64x64 per
// wave, acc[4][4] (64 AGPR), 32KB single-buffer LDS, syncthreads K-loop.
// Slot-XOR swizzle (T2, both-sides): linear LDS dest for global_load_lds,
// source k-slot pre-swizzled (slot ^= row&7), ds_read uses same XOR (G21).
// Delta 1: __launch_bounds__(256,3) -> min 3 waves/EU, reg cap 170 >= 148
// needed -> 3 blocks/CU co-resident (was 2) to hide the serial staging.
// Delta 2: EPI0 writes d to bf16 dtmp (half write traffic); EPI2 writes
// out = acc + by + dtmp with no out-RMW read.
template<int EPI>
__global__ __launch_bounds__(256, 3) void gemm_bt_kernel(
    const u16* __restrict__ A, const u16* __restrict__ Bt, int K,
    float* __restrict__ outA, float* __restrict__ outO, u16* __restrict__ dtmp,
    const float* __restrict__ b0, const float* __restrict__ b1,
    const float* __restrict__ b2, const float* __restrict__ b3) {
  __shared__ u16 ldsA[128*64];
  __shared__ u16 ldsB[128*64];
  const int tid = threadIdx.x;
  const int lane = tid & 63, wid = tid >> 6;
  const int wr = wid >> 1, wc = wid & 1;
  const int m0 = blockIdx.y * 128, n0 = blockIdx.x * 128;

  f32x4 acc[4][4] = {};

  // staging: lane l covers (row = g*8 + (l>>3), 16B slot = (l&7)^(l>>3))
  const int srow = lane >> 3;
  const int sq   = (lane & 7) ^ srow;
  const char* Ab = (const char*)A;
  const char* Bb = (const char*)Bt;

  // ds_read swizzle params
  const int kq  = lane >> 4;        // k-quarter within 32-wide half
  const int swz = lane & 7;         // == row&7 for all fragment rows
  const int arow = wr*64 + (lane & 15);
  const int brow = wc*64 + (lane & 15);

  for (int k0 = 0; k0 < K; k0 += 64) {
    #pragma unroll
    for (int i = 0; i < 4; ++i) {
      int g = wid*4 + i;
      int r = g*8 + srow;
      gload_lds16(Ab + ((size_t)(m0 + r)*K + k0 + sq*8)*2, (char*)ldsA + g*1024);
      gload_lds16(Bb + ((size_t)(n0 + r)*K + k0 + sq*8)*2, (char*)ldsB + g*1024);
    }
    __syncthreads();
    #pragma unroll
    for (int kk = 0; kk < 2; ++kk) {
      const int q = ((kk*4 + kq) ^ swz) * 8;   // swizzled element offset in row
      bf16x8 af[4], bfr[4];
      #pragma unroll
      for (int mi = 0; mi < 4; ++mi)
        af[mi]  = *(const bf16x8*)&ldsA[(arow + mi*16)*64 + q];
      #pragma unroll
      for (int ni = 0; ni < 4; ++ni)
        bfr[ni] = *(const bf16x8*)&ldsB[(brow + ni*16)*64 + q];
      #pragma unroll
      for (int mi = 0; mi < 4; ++mi)
        #pragma unroll
        for (int ni = 0; ni < 4; ++ni)
          acc[mi][ni] = __builtin_amdgcn_mfma_f32_16x16x32_bf16(af[mi], bfr[ni], acc[mi][ni], 0, 0, 0);
    }
    __syncthreads();
  }

  // epilogue: C/D layout col=lane&15, row=(lane>>4)*4+r  [m89-verified]
  const int crow = m0 + wr*64 + (lane >> 4)*4;
  const int ccol = wc*64 + (lane & 15);
  #pragma unroll
  for (int mi = 0; mi < 4; ++mi) {
    #pragma unroll
    for (int ni = 0; ni < 4; ++ni) {
      int coln = n0 + ccol + ni*16;
      #pragma unroll
      for (int r = 0; r < 4; ++r) {
        int row = crow + mi*16 + r;
        float v = acc[mi][ni][r];
        if (EPI == 0) {
          if (n0 < 768) {
            int seg = coln >> 8, cn = coln & 255;
            if (seg == 0)      v = 1.f / (1.f + __expf(-(v + b0[cn])));
            else if (seg == 1) v = v + b1[cn];
            else               v = tanhf(v + b2[cn]);
            outA[(size_t)row*768 + coln] = v;
          } else {
            int col = coln - 768;
            if (dtmp) dtmp[(size_t)row*1024 + col] = f2bf(v + b3[col]);
            else      outO[(size_t)row*1024 + col] = v + b3[col];
          }
        } else {
          const size_t o = (size_t)row*1024 + coln;
          if (dtmp) outO[o] = v + b0[coln] + bf2f(dtmp[o]);
          else      outO[o] = outO[o] + v + b0[coln];
        }
      }
    }
  }
}

// ---------------- scan: s_t = a*s + (1-a)*b ; cs = c*s ----------------
// abc layout: (m, 768) cols [0,256)=a (post-sigmoid), [256,512)=b, [512,768)=c (post-tanh)
__global__ void scanA_kernel(const float* __restrict__ abc,
                             float* __restrict__ Asum, float* __restrict__ Usum) {
  int idx = blockIdx.x * blockDim.x + threadIdx.x;    // chunk*2048 + chain
  int chain = idx & (CHAINS - 1);
  int ch = idx >> 11;
  int bb = chain >> 8, n = chain & 255;
  const float* base = abc + (size_t)(bb*Tt + ch*TC) * 768;
  float A = 1.f, U = 0.f;
  for (int t = 0; t < TC; ++t) {
    float a = base[(size_t)t*768 + n];
    float b = base[(size_t)t*768 + 256 + n];
    U = a*U + (1.f - a)*b;
    A *= a;
  }
  Asum[idx] = A; Usum[idx] = U;
}

__global__ void scanB_kernel(const float* __restrict__ Asum, const float* __restrict__ Usum,
                             float* __restrict__ Spre) {
  int chain = blockIdx.x * blockDim.x + threadIdx.x;  // 0..2047
  float s = 0.f;
  for (int ch = 0; ch < NCH; ++ch) {
    int i = (ch << 11) + chain;
    Spre[i] = s;
    s = Asum[i]*s + Usum[i];
  }
}

__global__ void scanC_kernel(const float* __restrict__ abc, const float* __restrict__ Spre,
                             u16* __restrict__ cs) {
  int idx = blockIdx.x * blockDim.x + threadIdx.x;
  int chain = idx & (CHAINS - 1);
  int ch = idx >> 11;
  int bb = chain >> 8, n = chain & 255;
  const float* base = abc + (size_t)(bb*Tt + ch*TC) * 768;
  u16* csb = cs + (size_t)(bb*Tt + ch*TC) * 256 + n;
  float s = Spre[idx];
  for (int t = 0; t < TC; ++t) {
    float a = base[(size_t)t*768 + n];
    float b = base[(size_t)t*768 + 256 + n];
    float c = base[(size_t)t*768 + 512 + n];
    s = a*s + (1.f - a)*b;
    csb[(size_t)t*256] = f2bf(c*s);
  }
}

extern "C" void kernel_launch(void* const* d_in, const int* in_sizes, int n_in,
                              void* d_out, int out_size, void* d_ws, size_t ws_size,
                              hipStream_t stream) {
  const float* x  = (const float*)d_in[0];
  const float* Wa = (const float*)d_in[1];
  const float* ba = (const float*)d_in[2];
  const float* Wb = (const float*)d_in[3];
  const float* bb = (const float*)d_in[4];
  const float* Wc = (const float*)d_in[5];
  const float* bc = (const float*)d_in[6];
  const float* Wd = (const float*)d_in[7];
  const float* bd = (const float*)d_in[8];
  const float* Wy = (const float*)d_in[9];
  const float* by = (const float*)d_in[10];
  float* out = (float*)d_out;
  char* ws = (char*)d_ws;

  // workspace layout (bytes)
  u16*  xb    = (u16*) (ws + 0);          // 33,554,432
  u16*  Wcomb = (u16*) (ws + 33554432);   //  3,670,016
  u16*  Wyt   = (u16*) (ws + 37224448);   //    524,288
  float* abc  = (float*)(ws + 37748736);  // 50,331,648
  u16*  cs    = (u16*) (ws + 88080384);   //  8,388,608
  float* Asum = (float*)(ws + 96468992);  //    262,144
  float* Usum = (float*)(ws + 96731136);  //    262,144
  float* Spre = (float*)(ws + 96993280);  //    262,144
  u16*  dtmp  = (ws_size >= WS_NEED) ? (u16*)(ws + 97255424) : nullptr; // 33,554,432

  // 1) convert x to bf16
  cvt_x_kernel<<<Mm*Dd/4/256, 256, 0, stream>>>(x, xb);
  // 2) pack weights (transposed bf16, [Wa|Wb|Wc|Wd] fused)
  pack_w_kernel<<<dim3(32, 32, 5), 256, 0, stream>>>(Wa, Wb, Wc, Wd, Wy, Wcomb, Wyt);
  // 3) fused GEMM: abc = act(x@[Wa|Wb|Wc]+bias), dtmp = x@Wd + bd (bf16)
  gemm_bt_kernel<0><<<dim3(NCOMB/128, Mm/128), 256, 0, stream>>>(
      xb, Wcomb, Dd, abc, out, dtmp, ba, bb, bc, bd);
  // 4) chunked scan
  scanA_kernel<<<CHAINS*NCH/256, 256, 0, stream>>>(abc, Asum, Usum);
  scanB_kernel<<<CHAINS/256, 256, 0, stream>>>(Asum, Usum, Spre);
  scanC_kernel<<<CHAINS*NCH/256, 256, 0, stream>>>(abc, Spre, cs);
  // 5) out = cs @ Wy + by + dtmp
  gemm_bt_kernel<2><<<dim3(Dd/128, Mm/128), 256, 0, stream>>>(
      cs, Wyt, Nn, nullptr, out, dtmp, by, nullptr, nullptr, nullptr);
}